// Round 1
// baseline (196.188 us; speedup 1.0000x reference)
//
#include <hip/hip_runtime.h>
#include <hip/hip_bf16.h>

typedef __attribute__((ext_vector_type(8))) short bf16x8;
typedef __attribute__((ext_vector_type(4))) float f32x4;

#define B_  512
#define N_  256
#define SD_ 1024
#define HD_ 512
#define AD_ 256

__device__ __forceinline__ unsigned short f2bf(float f) {
    unsigned int u = __float_as_uint(f);
    unsigned int r = (u + 0x7FFFu + ((u >> 16) & 1u)) >> 16;
    return (unsigned short)r;
}

// ---------------------------------------------------------------------------
// K0: pack Wh (AD x HD, f32, row-major) into bf16 B-fragment layout for
// mfma_f32_16x16x32_bf16. Fragment (ct, ks): 64 lanes x 8 bf16 contiguous.
// B[k][col] = Wh[col][k];  col = ct*16 + (lane&15), k = ks*32 + (lane>>4)*8 + i
__global__ void k0_pack(const float* __restrict__ Wh, unsigned short* __restrict__ whp) {
    int g = blockIdx.x * 256 + threadIdx.x;   // 16384 fragments-lanes total
    int ct  = g >> 10;
    int rem = g & 1023;
    int ks  = rem >> 6;
    int l   = rem & 63;
    int a   = ct * 16 + (l & 15);
    int kb  = ks * 32 + (l >> 4) * 8;
    const float* src = Wh + (size_t)a * HD_ + kb;
    float4 v0 = *(const float4*)(src);
    float4 v1 = *(const float4*)(src + 4);
    bf16x8 o;
    o[0] = (short)f2bf(v0.x); o[1] = (short)f2bf(v0.y);
    o[2] = (short)f2bf(v0.z); o[3] = (short)f2bf(v0.w);
    o[4] = (short)f2bf(v1.x); o[5] = (short)f2bf(v1.y);
    o[6] = (short)f2bf(v1.z); o[7] = (short)f2bf(v1.w);
    ((bf16x8*)whp)[g] = o;
}

// ---------------------------------------------------------------------------
// K1: per b: sp = state@Ws^T + bs (fp32), sn = max(||sp||,eps),
//            q = Wh^T sp, c = sp.bh
__global__ __launch_bounds__(256) void k1_proj(
    const float* __restrict__ state, const float* __restrict__ Ws,
    const float* __restrict__ bs, const float* __restrict__ Wh,
    const float* __restrict__ bh,
    float* __restrict__ sp, float* __restrict__ sn,
    float* __restrict__ qv, float* __restrict__ cv)
{
    __shared__ float st[SD_];
    __shared__ float spl[AD_];
    __shared__ float red[AD_];
    int tid = threadIdx.x;
    int b = blockIdx.x;
    ((float4*)st)[tid] = ((const float4*)(state + (size_t)b * SD_))[tid];
    __syncthreads();
    float acc = bs[tid];
    const float* wr = Ws + (size_t)tid * SD_;
    #pragma unroll 8
    for (int k = 0; k < SD_; k += 4) {
        float4 w4 = *(const float4*)(wr + k);
        acc += w4.x * st[k] + w4.y * st[k+1] + w4.z * st[k+2] + w4.w * st[k+3];
    }
    spl[tid] = acc;
    sp[(size_t)b * AD_ + tid] = acc;
    red[tid] = acc * acc;
    __syncthreads();
    for (int s = 128; s > 0; s >>= 1) { if (tid < s) red[tid] += red[tid + s]; __syncthreads(); }
    if (tid == 0) sn[b] = fmaxf(sqrtf(red[0]), 1e-8f);
    __syncthreads();
    red[tid] = acc * bh[tid];
    __syncthreads();
    for (int s = 128; s > 0; s >>= 1) { if (tid < s) red[tid] += red[tid + s]; __syncthreads(); }
    if (tid == 0) cv[b] = red[0];
    // q[h] = sum_a sp[a] * Wh[a][h]  (coalesced over h)
    float q0 = 0.f, q1 = 0.f;
    for (int a = 0; a < AD_; ++a) {
        float s = spl[a];
        q0 += s * Wh[(size_t)a * HD_ + tid];
        q1 += s * Wh[(size_t)a * HD_ + tid + 256];
    }
    qv[(size_t)b * HD_ + tid] = q0;
    qv[(size_t)b * HD_ + tid + 256] = q1;
}

// ---------------------------------------------------------------------------
// K2: per 64 hint-rows (one b per block since 64|256): compute
//   norm2[m] = || hints_row @ Wh^T + bh ||^2  via bf16 MFMA (HP never stored)
//   num[m]   = q[b].hint_row (fp32)
//   score    = (num + c) / (sn * max(sqrt(norm2),eps))
__device__ __forceinline__ int lds_off(int row, int kbyte) {
    return row * 512 + (kbyte ^ ((row & 7) << 4));   // 16B-block XOR swizzle (G4)
}

__global__ __launch_bounds__(256) void k2_scores(
    const float* __restrict__ hints, const unsigned short* __restrict__ whp,
    const float* __restrict__ qv, const float* __restrict__ cv,
    const float* __restrict__ sn, const float* __restrict__ bh,
    float* __restrict__ scores)
{
    __shared__ unsigned short A_bf[64 * 256];   // 32 KB, one K-chunk (256) of 64 rows
    __shared__ float q_lds[HD_];
    __shared__ float bh_lds[AD_];
    __shared__ float norm2_lds[4][64];
    __shared__ float num_lds[64][4];
    int tid = threadIdx.x;
    int lane = tid & 63;
    int w = tid >> 6;
    int m0 = blockIdx.x * 64;
    int b = m0 >> 8;
    if (tid < 128) ((float4*)q_lds)[tid] = ((const float4*)(qv + (size_t)b * HD_))[tid];
    if (tid >= 192) ((float4*)bh_lds)[tid - 192] = ((const float4*)bh)[tid - 192];
    int row = tid >> 2, qq = tid & 3;
    const float* arow = hints + (size_t)(m0 + row) * HD_;
    f32x4 acc[4][4];
    #pragma unroll
    for (int i = 0; i < 4; ++i)
        #pragma unroll
        for (int j = 0; j < 4; ++j) acc[i][j] = (f32x4){0.f, 0.f, 0.f, 0.f};
    float num_reg = 0.f;
    __syncthreads();

    for (int kc = 0; kc < 2; ++kc) {
        // stage 64x256 f32 -> bf16 LDS (swizzled); fold in fp32 num partial
        #pragma unroll 4
        for (int j = 0; j < 16; ++j) {
            int kl = qq * 64 + j * 4;
            int kg = kc * 256 + kl;
            float4 v = *(const float4*)(arow + kg);
            num_reg += v.x * q_lds[kg] + v.y * q_lds[kg+1] + v.z * q_lds[kg+2] + v.w * q_lds[kg+3];
            ushort4 u;
            u.x = f2bf(v.x); u.y = f2bf(v.y); u.z = f2bf(v.z); u.w = f2bf(v.w);
            *(ushort4*)((char*)A_bf + lds_off(row, kl * 2)) = u;
        }
        __syncthreads();
        #pragma unroll
        for (int ks8 = 0; ks8 < 8; ++ks8) {
            int ks = kc * 8 + ks8;
            bf16x8 bfr[4], afr[4];
            #pragma unroll
            for (int ni = 0; ni < 4; ++ni) {
                int ct = w * 4 + ni;
                bfr[ni] = ((const bf16x8*)whp)[(ct * 16 + ks) * 64 + lane];
            }
            #pragma unroll
            for (int mi = 0; mi < 4; ++mi)
                afr[mi] = *(const bf16x8*)((const char*)A_bf +
                          lds_off(mi * 16 + (lane & 15), ks8 * 64 + (lane >> 4) * 16));
            #pragma unroll
            for (int mi = 0; mi < 4; ++mi)
                #pragma unroll
                for (int ni = 0; ni < 4; ++ni)
                    acc[mi][ni] = __builtin_amdgcn_mfma_f32_16x16x32_bf16(
                        afr[mi], bfr[ni], acc[mi][ni], 0, 0, 0);
        }
        __syncthreads();
    }
    num_lds[row][qq] = num_reg;

    // reduce HP tile -> row norms.  C layout: col = lane&15, row = (lane>>4)*4 + r
    float nrm[4][4];
    #pragma unroll
    for (int i = 0; i < 4; ++i)
        #pragma unroll
        for (int r = 0; r < 4; ++r) nrm[i][r] = 0.f;
    #pragma unroll
    for (int mi = 0; mi < 4; ++mi)
        #pragma unroll
        for (int ni = 0; ni < 4; ++ni) {
            float bhv = bh_lds[w * 64 + ni * 16 + (lane & 15)];
            #pragma unroll
            for (int r = 0; r < 4; ++r) {
                float hp = acc[mi][ni][r] + bhv;
                nrm[mi][r] += hp * hp;
            }
        }
    #pragma unroll
    for (int mi = 0; mi < 4; ++mi)
        #pragma unroll
        for (int r = 0; r < 4; ++r) {
            float v = nrm[mi][r];
            v += __shfl_xor(v, 1); v += __shfl_xor(v, 2);
            v += __shfl_xor(v, 4); v += __shfl_xor(v, 8);
            nrm[mi][r] = v;
        }
    if ((lane & 15) == 0) {
        #pragma unroll
        for (int mi = 0; mi < 4; ++mi)
            #pragma unroll
            for (int r = 0; r < 4; ++r)
                norm2_lds[w][mi * 16 + ((lane >> 4) << 2) + r] = nrm[mi][r];
    }
    __syncthreads();
    if (tid < 64) {
        float n2 = norm2_lds[0][tid] + norm2_lds[1][tid] + norm2_lds[2][tid] + norm2_lds[3][tid];
        float numv = num_lds[tid][0] + num_lds[tid][1] + num_lds[tid][2] + num_lds[tid][3];
        float hn = fmaxf(sqrtf(n2), 1e-8f);
        scores[m0 + tid] = (numv + cv[b]) / (sn[b] * hn);
    }
}

// ---------------------------------------------------------------------------
// K34: per b: softmax over 256 scores, then out[h] = sum_n w[n]*hints[b,n,h]
__global__ __launch_bounds__(256) void k34_softmax_out(
    const float* __restrict__ hints, const float* __restrict__ scores,
    float* __restrict__ out)
{
    __shared__ float wsm[N_];
    __shared__ float red[N_];
    int tid = threadIdx.x;
    int b = blockIdx.x;
    float s = scores[(size_t)b * N_ + tid];
    red[tid] = s;
    __syncthreads();
    for (int st = 128; st > 0; st >>= 1) { if (tid < st) red[tid] = fmaxf(red[tid], red[tid + st]); __syncthreads(); }
    float m = red[0];
    __syncthreads();
    float e = __expf(s - m);
    red[tid] = e;
    __syncthreads();
    for (int st = 128; st > 0; st >>= 1) { if (tid < st) red[tid] += red[tid + st]; __syncthreads(); }
    wsm[tid] = e / red[0];
    __syncthreads();
    const float* hb = hints + (size_t)b * N_ * HD_;
    float a0 = 0.f, a1 = 0.f;
    int h0 = tid * 2;
    #pragma unroll 8
    for (int n = 0; n < N_; ++n) {
        float2 v = *(const float2*)(hb + (size_t)n * HD_ + h0);
        float wn = wsm[n];
        a0 += wn * v.x; a1 += wn * v.y;
    }
    out[(size_t)b * HD_ + h0]     = a0;
    out[(size_t)b * HD_ + h0 + 1] = a1;
}

// ---------------------------------------------------------------------------
extern "C" void kernel_launch(void* const* d_in, const int* in_sizes, int n_in,
                              void* d_out, int out_size, void* d_ws, size_t ws_size,
                              hipStream_t stream) {
    const float* state = (const float*)d_in[0];
    const float* hints = (const float*)d_in[1];
    const float* Ws    = (const float*)d_in[2];
    const float* bs    = (const float*)d_in[3];
    const float* Wh    = (const float*)d_in[4];
    const float* bh    = (const float*)d_in[5];
    float* out = (float*)d_out;

    // workspace layout (~2.26 MB)
    float* sp = (float*)d_ws;                      // B*AD
    float* sn = sp + B_ * AD_;                     // B
    float* qv = sn + B_;                           // B*HD
    float* cv = qv + (size_t)B_ * HD_;             // B
    unsigned short* whp = (unsigned short*)(cv + B_);   // AD*HD bf16
    float* scores = (float*)(whp + (size_t)AD_ * HD_);  // B*N

    k0_pack<<<64, 256, 0, stream>>>(Wh, whp);
    k1_proj<<<B_, 256, 0, stream>>>(state, Ws, bs, Wh, bh, sp, sn, qv, cv);
    k2_scores<<<(B_ * N_) / 64, 256, 0, stream>>>(hints, whp, qv, cv, sn, bh, scores);
    k34_softmax_out<<<B_, 256, 0, stream>>>(hints, scores, out);
}

// Round 2
// 184.059 us; speedup vs baseline: 1.0659x; 1.0659x over previous
//
#include <hip/hip_runtime.h>
#include <hip/hip_bf16.h>

typedef __attribute__((ext_vector_type(8))) short bf16x8;
typedef __attribute__((ext_vector_type(4))) float f32x4;

#define B_  512
#define N_  256
#define SD_ 1024
#define HD_ 512
#define AD_ 256

__device__ __forceinline__ unsigned short f2bf(float f) {
    unsigned int u = __float_as_uint(f);
    unsigned int r = (u + 0x7FFFu + ((u >> 16) & 1u)) >> 16;
    return (unsigned short)r;
}

// ---------------------------------------------------------------------------
// K0: pack Wh (AD x HD, f32, row-major) into bf16 B-fragment layout for
// mfma_f32_16x16x32_bf16. Fragment (ct, ks): 64 lanes x 8 bf16 contiguous.
// B[k][col] = Wh[col][k];  col = ct*16 + (lane&15), k = ks*32 + (lane>>4)*8 + i
__global__ void k0_pack(const float* __restrict__ Wh, unsigned short* __restrict__ whp) {
    int g = blockIdx.x * 256 + threadIdx.x;   // 16384 fragment-lanes total
    int ct  = g >> 10;
    int rem = g & 1023;
    int ks  = rem >> 6;
    int l   = rem & 63;
    int a   = ct * 16 + (l & 15);
    int kb  = ks * 32 + (l >> 4) * 8;
    const float* src = Wh + (size_t)a * HD_ + kb;
    float4 v0 = *(const float4*)(src);
    float4 v1 = *(const float4*)(src + 4);
    bf16x8 o;
    o[0] = (short)f2bf(v0.x); o[1] = (short)f2bf(v0.y);
    o[2] = (short)f2bf(v0.z); o[3] = (short)f2bf(v0.w);
    o[4] = (short)f2bf(v1.x); o[5] = (short)f2bf(v1.y);
    o[6] = (short)f2bf(v1.z); o[7] = (short)f2bf(v1.w);
    ((bf16x8*)whp)[g] = o;
}

// ---------------------------------------------------------------------------
// K1: 2 b's per block, 512 threads (8 waves).
//   sp = state@Ws^T + bs  (wave-per-a, COALESCED Ws reads, state in regs)
//   sn = max(||sp||,eps);  cv = sp.bh;  q = Wh^T sp  (coalesced over h)
__global__ __launch_bounds__(512) void k1_proj(
    const float* __restrict__ state, const float* __restrict__ Ws,
    const float* __restrict__ bs, const float* __restrict__ Wh,
    const float* __restrict__ bh,
    float* __restrict__ sn, float* __restrict__ qv, float* __restrict__ cv)
{
    __shared__ float st[2][SD_];     // 8KB
    __shared__ float spl[2][AD_];    // 2KB
    __shared__ float red[2][AD_];    // 2KB
    int tid = threadIdx.x, lane = tid & 63, w = tid >> 6;
    int b0 = blockIdx.x * 2;
    ((float4*)st)[tid] = ((const float4*)(state + (size_t)b0 * SD_))[tid];
    __syncthreads();
    float4 s0[4], s1[4];
    #pragma unroll
    for (int seg = 0; seg < 4; ++seg) {
        s0[seg] = *(const float4*)&st[0][seg * 256 + lane * 4];
        s1[seg] = *(const float4*)&st[1][seg * 256 + lane * 4];
    }
    // each wave handles 32 a's; lanes read Ws[a] coalesced (64 lanes x 16B)
    #pragma unroll 2
    for (int i = 0; i < 32; ++i) {
        int a = w * 32 + i;
        const float4* wr = (const float4*)(Ws + (size_t)a * SD_);
        float p0 = 0.f, p1 = 0.f;
        #pragma unroll
        for (int seg = 0; seg < 4; ++seg) {
            float4 wv = wr[seg * 64 + lane];
            p0 += wv.x * s0[seg].x + wv.y * s0[seg].y + wv.z * s0[seg].z + wv.w * s0[seg].w;
            p1 += wv.x * s1[seg].x + wv.y * s1[seg].y + wv.z * s1[seg].z + wv.w * s1[seg].w;
        }
        #pragma unroll
        for (int d = 1; d < 64; d <<= 1) { p0 += __shfl_xor(p0, d); p1 += __shfl_xor(p1, d); }
        if (lane == 0) {
            float bsa = bs[a];
            spl[0][a] = p0 + bsa;
            spl[1][a] = p1 + bsa;
        }
    }
    __syncthreads();
    int tb = tid >> 8, t = tid & 255;
    float sv = spl[tb][t];
    red[tb][t] = sv * sv;
    __syncthreads();
    for (int s = 128; s > 0; s >>= 1) { if (t < s) red[tb][t] += red[tb][t + s]; __syncthreads(); }
    if (t == 0) sn[b0 + tb] = fmaxf(sqrtf(red[tb][0]), 1e-8f);
    __syncthreads();
    red[tb][t] = sv * bh[t];
    __syncthreads();
    for (int s = 128; s > 0; s >>= 1) { if (t < s) red[tb][t] += red[tb][t + s]; __syncthreads(); }
    if (t == 0) cv[b0 + tb] = red[tb][0];
    // q[h] for both b's; one coalesced Wh load serves both
    float q0 = 0.f, q1 = 0.f;
    #pragma unroll 8
    for (int a = 0; a < AD_; ++a) {
        float wv = Wh[(size_t)a * HD_ + tid];
        q0 += spl[0][a] * wv;
        q1 += spl[1][a] * wv;
    }
    qv[(size_t)b0 * HD_ + tid] = q0;
    qv[(size_t)(b0 + 1) * HD_ + tid] = q1;
}

// ---------------------------------------------------------------------------
// K2 fused: one block per b (512 threads, 8 waves).
//   M-chunked (2 x 128 rows), K-chunked (4 x 128), double-buffered bf16 LDS.
//   scores -> softmax -> weighted sum (hints re-read is L2/L3-warm).
__device__ __forceinline__ void stage_write(
    unsigned short* Ab, const float4* v, int row, int q4, int kc,
    float& num_reg, const float* q_lds)
{
    #pragma unroll
    for (int j = 0; j < 8; ++j) {
        int kl = q4 * 32 + j * 4;
        float4 qq = *(const float4*)(q_lds + kc * 128 + kl);
        float4 x = v[j];
        num_reg += x.x * qq.x + x.y * qq.y + x.z * qq.z + x.w * qq.w;
        ushort4 u;
        u.x = f2bf(x.x); u.y = f2bf(x.y); u.z = f2bf(x.z); u.w = f2bf(x.w);
        *(ushort4*)((char*)Ab + row * 256 + ((kl * 2) ^ ((row & 7) << 4))) = u;
    }
}

__global__ __launch_bounds__(512, 2) void k2_fused(
    const float* __restrict__ hints, const unsigned short* __restrict__ whp,
    const float* __restrict__ qv, const float* __restrict__ cv,
    const float* __restrict__ sn, const float* __restrict__ bh,
    float* __restrict__ out)
{
    __shared__ unsigned short A_bf[2][128 * 128];  // 64KB, double-buffered
    __shared__ float q_lds[HD_];                   // 2KB
    __shared__ float bh_lds[AD_];                  // 1KB
    __shared__ float norm2p[8][128];               // 4KB
    __shared__ float num_lds[128][4];              // 2KB
    __shared__ float sc[N_];                       // 1KB
    __shared__ float red[N_];                      // 1KB
    __shared__ float wsm[N_];                      // 1KB

    int tid = threadIdx.x, lane = tid & 63, w = tid >> 6;
    int b = blockIdx.x;
    const float* hb = hints + (size_t)b * N_ * HD_;
    if (tid < 128) ((float4*)q_lds)[tid] = ((const float4*)(qv + (size_t)b * HD_))[tid];
    else if (tid < 192) ((float4*)bh_lds)[tid - 128] = ((const float4*)bh)[tid - 128];
    float cvb = cv[b];
    float snb = sn[b];
    int row = tid >> 2, q4 = tid & 3;   // staging: 128 rows x 4 col-groups
    __syncthreads();

    for (int mc = 0; mc < 2; ++mc) {
        f32x4 acc[8][2];
        #pragma unroll
        for (int mf = 0; mf < 8; ++mf) {
            acc[mf][0] = (f32x4){0.f, 0.f, 0.f, 0.f};
            acc[mf][1] = (f32x4){0.f, 0.f, 0.f, 0.f};
        }
        float num_reg = 0.f;
        const float* arow = hb + (size_t)(mc * 128 + row) * HD_;
        float4 v[8];
        // prologue: chunk 0
        #pragma unroll
        for (int j = 0; j < 8; ++j) v[j] = *(const float4*)(arow + q4 * 32 + j * 4);
        stage_write(A_bf[0], v, row, q4, 0, num_reg, q_lds);
        __syncthreads();
        for (int kc = 0; kc < 4; ++kc) {
            // issue next chunk's loads early (hide HBM under MFMA)
            if (kc < 3) {
                #pragma unroll
                for (int j = 0; j < 8; ++j)
                    v[j] = *(const float4*)(arow + (kc + 1) * 128 + q4 * 32 + j * 4);
            }
            // MFMA on current buffer
            const unsigned short* Ab = A_bf[kc & 1];
            int kc4 = kc * 4;
            #pragma unroll
            for (int ks = 0; ks < 4; ++ks) {
                bf16x8 bfr0 = ((const bf16x8*)whp)[((2 * w + 0) * 16 + kc4 + ks) * 64 + lane];
                bf16x8 bfr1 = ((const bf16x8*)whp)[((2 * w + 1) * 16 + kc4 + ks) * 64 + lane];
                #pragma unroll
                for (int mf = 0; mf < 8; ++mf) {
                    int r = mf * 16 + (lane & 15);
                    bf16x8 afr = *(const bf16x8*)((const char*)Ab + r * 256 +
                                 ((ks * 64 + (lane >> 4) * 16) ^ ((r & 7) << 4)));
                    acc[mf][0] = __builtin_amdgcn_mfma_f32_16x16x32_bf16(afr, bfr0, acc[mf][0], 0, 0, 0);
                    acc[mf][1] = __builtin_amdgcn_mfma_f32_16x16x32_bf16(afr, bfr1, acc[mf][1], 0, 0, 0);
                }
            }
            if (kc < 3) stage_write(A_bf[(kc + 1) & 1], v, row, q4, kc + 1, num_reg, q_lds);
            __syncthreads();
        }
        num_lds[row][q4] = num_reg;
        // norm phase: C layout col = ct*16+(lane&15), row = mf*16+(lane>>4)*4+r
        int q4l = lane >> 4;
        float bh0 = bh_lds[(2 * w + 0) * 16 + (lane & 15)];
        float bh1 = bh_lds[(2 * w + 1) * 16 + (lane & 15)];
        #pragma unroll
        for (int mf = 0; mf < 8; ++mf) {
            #pragma unroll
            for (int r = 0; r < 4; ++r) {
                float h0 = acc[mf][0][r] + bh0;
                float h1 = acc[mf][1][r] + bh1;
                float vv = h0 * h0 + h1 * h1;
                vv += __shfl_xor(vv, 1); vv += __shfl_xor(vv, 2);
                vv += __shfl_xor(vv, 4); vv += __shfl_xor(vv, 8);
                if ((lane & 15) == 0) norm2p[w][mf * 16 + q4l * 4 + r] = vv;
            }
        }
        __syncthreads();
        if (tid < 128) {
            float n2 = 0.f;
            #pragma unroll
            for (int ww = 0; ww < 8; ++ww) n2 += norm2p[ww][tid];
            float nm = num_lds[tid][0] + num_lds[tid][1] + num_lds[tid][2] + num_lds[tid][3];
            float hn = fmaxf(sqrtf(n2), 1e-8f);
            sc[mc * 128 + tid] = (nm + cvb) / (snb * hn);
        }
        __syncthreads();
    }

    // softmax over sc[256]
    if (tid < 256) red[tid] = sc[tid];
    __syncthreads();
    for (int s = 128; s > 0; s >>= 1) { if (tid < s) red[tid] = fmaxf(red[tid], red[tid + s]); __syncthreads(); }
    float mx = red[0];
    __syncthreads();
    if (tid < 256) { float e = __expf(sc[tid] - mx); sc[tid] = e; red[tid] = e; }
    __syncthreads();
    for (int s = 128; s > 0; s >>= 1) { if (tid < s) red[tid] += red[tid + s]; __syncthreads(); }
    float inv = 1.f / red[0];
    __syncthreads();
    if (tid < 256) wsm[tid] = sc[tid] * inv;
    __syncthreads();

    // weighted sum over ORIGINAL hints (L2/L3-warm re-read); h = tid
    float acc_o = 0.f;
    #pragma unroll 8
    for (int n = 0; n < N_; ++n)
        acc_o += wsm[n] * hb[(size_t)n * HD_ + tid];
    out[(size_t)b * HD_ + tid] = acc_o;
}

// ---------------------------------------------------------------------------
extern "C" void kernel_launch(void* const* d_in, const int* in_sizes, int n_in,
                              void* d_out, int out_size, void* d_ws, size_t ws_size,
                              hipStream_t stream) {
    const float* state = (const float*)d_in[0];
    const float* hints = (const float*)d_in[1];
    const float* Ws    = (const float*)d_in[2];
    const float* bs    = (const float*)d_in[3];
    const float* Wh    = (const float*)d_in[4];
    const float* bh    = (const float*)d_in[5];
    float* out = (float*)d_out;

    // workspace layout (~1.3 MB)
    float* sn = (float*)d_ws;                          // B
    float* cv = sn + B_;                               // B
    float* qv = cv + B_;                               // B*HD
    unsigned short* whp = (unsigned short*)(qv + (size_t)B_ * HD_);  // AD*HD bf16

    k0_pack<<<64, 256, 0, stream>>>(Wh, whp);
    k1_proj<<<B_ / 2, 512, 0, stream>>>(state, Ws, bs, Wh, bh, sn, qv, cv);
    k2_fused<<<B_, 512, 0, stream>>>(hints, whp, qv, cv, sn, bh, out);
}